// Round 4
// baseline (1625.786 us; speedup 1.0000x reference)
//
#include <hip/hip_runtime.h>
#include <stdint.h>

// ---------- bf16 helpers (manual, no hip_bf16 dependency) ----------
static __device__ __forceinline__ float b2f(uint16_t b){
    return __uint_as_float(((uint32_t)b) << 16);
}
static __device__ __forceinline__ uint16_t f2b(float f){
    uint32_t u = __float_as_uint(f);
    return (uint16_t)((u + 0x7fffu + ((u >> 16) & 1u)) >> 16);
}

// ---------- sentinel fill ----------
__global__ void k_sentinel(uint32_t* out, int nwords, uint32_t pat){
    int i = blockIdx.x * blockDim.x + threadIdx.x;
    if (i < nwords) out[i] = pat;
}

// ---------- dtype flags: flags[0]=edge_is_int64, flags[1]=x_is_bf16 ----------
__global__ void k_flags(const uint32_t* xw, const int* ei, int* flags){
    if (threadIdx.x != 0 || blockIdx.x != 0) return;
    int odd_nz = 0;
    for (int k = 0; k < 128; k++){
        if (ei[2 * k + 1] != 0) odd_nz = 1;
    }
    flags[0] = odd_nz ? 0 : 1;   // all odd 32-bit words zero => int64 indices
    int big = 0;
    for (int k = 0; k < 128; k++){
        float lo = __uint_as_float(xw[k] << 16);   // low 16 bits decoded as bf16
        if (!(fabsf(lo) <= 1024.0f)) big = 1;      // catches huge/NaN/Inf
    }
    flags[1] = big ? 0 : 1;      // all low-halves sane bf16 values => packed bf16
}

__global__ void k_zero(int* p, int n){
    int i = blockIdx.x * blockDim.x + threadIdx.x;
    if (i < n) p[i] = 0;
}

// ---------- CSR build ----------
__global__ void k_deg(const int* ei, int E, int* deg, const int* flags){
    int e = blockIdx.x * blockDim.x + threadIdx.x;
    if (e < E){
        int d = flags[0] ? ei[2 * e] : ei[e];
        atomicAdd(&deg[d], 1);
    }
}

__global__ void k_scan(const int* deg, int N, int* rp, int* cur){
    __shared__ int sums[256];
    int t = threadIdx.x;
    int chunk = (N + 255) / 256;
    int s0 = t * chunk;
    int e0 = s0 + chunk; if (e0 > N) e0 = N; if (s0 > N) s0 = N;
    int s = 0;
    for (int i = s0; i < e0; i++) s += deg[i];
    sums[t] = s;
    __syncthreads();
    for (int off = 1; off < 256; off <<= 1){
        int v = (t >= off) ? sums[t - off] : 0;
        __syncthreads();
        sums[t] += v;
        __syncthreads();
    }
    int run = sums[t] - s;   // exclusive prefix
    for (int i = s0; i < e0; i++){
        rp[i] = run; cur[i] = run; run += deg[i];
    }
    if (t == 255) rp[N] = sums[255];
}

__global__ void k_fill(const int* ei, int E, int* cur, int* col, const int* flags){
    int e = blockIdx.x * blockDim.x + threadIdx.x;
    if (e < E){
        int is64 = flags[0];
        int d = is64 ? ei[2 * e] : ei[e];
        int sv = is64 ? ei[2 * (E + e)] : ei[E + e];
        int p = atomicAdd(&cur[d], 1);
        col[p] = sv;
    }
}

// ---------- input conversions ----------
__global__ void k_cvt_x(const void* x, uint16_t* hx, int n, const int* flags){
    int i = blockIdx.x * blockDim.x + threadIdx.x;
    if (i >= n) return;
    if (flags[1]) hx[i] = ((const uint16_t*)x)[i];
    else          hx[i] = f2b(((const float*)x)[i]);
}

__global__ void k_cvt_f(const void* w, float* wc, int n, const int* flags){
    int i = blockIdx.x * blockDim.x + threadIdx.x;
    if (i >= n) return;
    if (flags[1]) wc[i] = b2f(((const uint16_t*)w)[i]);
    else          wc[i] = ((const float*)w)[i];
}

// ---------- aggregation: agg[i,f] = h[i,f] + sum_{j in nbr(i)} h[j,f] ----------
__global__ void k_agg(const uint16_t* hx, const int* rp, const int* col,
                      uint16_t* agg, int N){
    int i = blockIdx.x;
    int t = threadIdx.x;          // 128 threads = feature index
    if (i >= N) return;
    float a = b2f(hx[(size_t)i * 128 + t]);
    int s = rp[i], e = rp[i + 1];
    for (int k = s; k < e; k++){
        int j = col[k];
        a += b2f(hx[(size_t)j * 128 + t]);
    }
    agg[(size_t)i * 128 + t] = f2b(a);
}

// ---------- GEMM (in place on agg): y[i,t] = bias[t] + sum_k a[i,k] * W[k,t] ----------
__global__ void k_gemm(uint16_t* agg, const float* wc, const float* bias, int N){
    __shared__ float arow[128];
    int i = blockIdx.x;
    int t = threadIdx.x;          // 128 threads = output feature
    if (i >= N) return;
    arow[t] = b2f(agg[(size_t)i * 128 + t]);
    __syncthreads();
    float y = bias[t];
    #pragma unroll 8
    for (int k = 0; k < 128; k++){
        y += arow[k] * wc[k * 128 + t];
    }
    agg[(size_t)i * 128 + t] = f2b(y);
}

// ---------- column stats ----------
__global__ void k_colstats(const uint16_t* Y, float* colsum, float* colssq, int N){
    int t = threadIdx.x;          // 256 threads
    int c = t & 127;
    int half = t >> 7;
    float s = 0.f, ss = 0.f;
    for (int r = blockIdx.x * 2 + half; r < N; r += 512){
        float y = b2f(Y[(size_t)r * 128 + c]);
        s += y; ss += y * y;
    }
    atomicAdd(&colsum[c], s);
    atomicAdd(&colssq[c], ss);
}

__global__ void k_meaninv(const float* colsum, const float* colssq, float ninv,
                          float* meanv, float* invv){
    int c = threadIdx.x;          // 128 threads
    float m = colsum[c] * ninv;
    float v = colssq[c] * ninv - m * m;
    meanv[c] = m;
    invv[c] = rsqrtf(v + 1e-5f);
}

// ---------- BN + ReLU ----------
__global__ void k_bn(const uint16_t* Y, const float* meanv, const float* invv,
                     uint16_t* hx, int n){
    int idx = blockIdx.x * blockDim.x + threadIdx.x;
    if (idx >= n) return;
    int c = idx & 127;
    float v = b2f(Y[idx]);
    float r = (v - meanv[c]) * invv[c];
    if (r < 0.f) r = 0.f;
    hx[idx] = f2b(r);
}

// ---------- final linear 128 -> 40 ----------
__global__ void k_final(const uint16_t* hx, const float* wc, const float* bias,
                        void* out, int N, const int* flags){
    int idx = blockIdx.x * blockDim.x + threadIdx.x;
    if (idx >= N * 40) return;
    int i = idx / 40;
    int c = idx % 40;
    float y = bias[c];
    const uint16_t* row = hx + (size_t)i * 128;
    #pragma unroll 8
    for (int k = 0; k < 128; k++){
        y += b2f(row[k]) * wc[k * 40 + c];
    }
    if (flags[1]) ((uint16_t*)out)[idx] = f2b(y);
    else          ((float*)out)[idx] = y;
}

extern "C" void kernel_launch(void* const* d_in, const int* in_sizes, int n_in,
                              void* d_out, int out_size, void* d_ws, size_t ws_size,
                              hipStream_t stream){
    (void)n_in;
    const void* x  = d_in[0];
    const int* ei  = (const int*)d_in[1];
    const void* W0 = d_in[2];
    const void* b0 = d_in[3];
    const void* W1 = d_in[4];
    const void* b1 = d_in[5];
    const void* W2 = d_in[6];
    const void* b2 = d_in[7];
    const void* Wl = d_in[8];
    const void* bl = d_in[9];

    const int N = in_sizes[0] / 128;
    const int E = in_sizes[1] / 2;
    const int NF = N * 128;

    // ---- workspace layout (manual offsets, 256 B aligned) ----
    char* ws = (char*)d_ws;
    size_t off = 0;
    uint16_t* hx = (uint16_t*)(ws + off); off += ((size_t)NF * 2 + 255) & ~(size_t)255;
    uint16_t* ag = (uint16_t*)(ws + off); off += ((size_t)NF * 2 + 255) & ~(size_t)255;
    int* col     = (int*)(ws + off);      off += ((size_t)E * 4 + 255) & ~(size_t)255;
    int* rp      = (int*)(ws + off);      off += ((size_t)(N + 1) * 4 + 255) & ~(size_t)255;
    int* cur     = (int*)(ws + off);      off += ((size_t)N * 4 + 255) & ~(size_t)255;
    int* deg     = (int*)(ws + off);      off += ((size_t)N * 4 + 255) & ~(size_t)255;
    int* flags   = (int*)(ws + off);      off += 256;
    float* wc0   = (float*)(ws + off);    off += 16384 * 4;
    float* wc1   = (float*)(ws + off);    off += 16384 * 4;
    float* wc2   = (float*)(ws + off);    off += 16384 * 4;
    float* wcl   = (float*)(ws + off);    off += 5120 * 4;
    float* bc0   = (float*)(ws + off);    off += 512;
    float* bc1   = (float*)(ws + off);    off += 512;
    float* bc2   = (float*)(ws + off);    off += 512;
    float* bcl   = (float*)(ws + off);    off += 256;
    float* colsum = (float*)(ws + off);   off += 512;
    float* colssq = (float*)(ws + off);   off += 512;
    float* meanv  = (float*)(ws + off);   off += 512;
    float* invv   = (float*)(ws + off);   off += 512;
    const size_t required = off;

    const int nwords = out_size / 2;   // safe for both bf16 (full) and fp32 (half) buffers
    const int fill_blocks = (nwords + 255) / 256;

    if (ws_size < required){
        k_sentinel<<<fill_blocks, 256, 0, stream>>>((uint32_t*)d_out, nwords, 0x40004000u); // 2.0
        return;
    }
    k_sentinel<<<fill_blocks, 256, 0, stream>>>((uint32_t*)d_out, nwords, 0x3F803F80u);     // 1.0

    // ---- flags + CSR ----
    k_flags<<<1, 64, 0, stream>>>((const uint32_t*)x, ei, flags);
    k_zero<<<(N + 255) / 256, 256, 0, stream>>>(deg, N);
    k_deg<<<(E + 255) / 256, 256, 0, stream>>>(ei, E, deg, flags);
    k_scan<<<1, 256, 0, stream>>>(deg, N, rp, cur);
    k_fill<<<(E + 255) / 256, 256, 0, stream>>>(ei, E, cur, col, flags);

    // ---- conversions ----
    k_cvt_x<<<(NF + 255) / 256, 256, 0, stream>>>(x, hx, NF, flags);
    k_cvt_f<<<64, 256, 0, stream>>>(W0, wc0, 16384, flags);
    k_cvt_f<<<64, 256, 0, stream>>>(W1, wc1, 16384, flags);
    k_cvt_f<<<64, 256, 0, stream>>>(W2, wc2, 16384, flags);
    k_cvt_f<<<20, 256, 0, stream>>>(Wl, wcl, 5120, flags);
    k_cvt_f<<<1, 128, 0, stream>>>(b0, bc0, 128, flags);
    k_cvt_f<<<1, 128, 0, stream>>>(b1, bc1, 128, flags);
    k_cvt_f<<<1, 128, 0, stream>>>(b2, bc2, 128, flags);
    k_cvt_f<<<1, 64, 0, stream>>>(bl, bcl, 40, flags);

    const float ninv = 1.0f / (float)N;
    float* wcs[3] = {wc0, wc1, wc2};
    float* bcs[3] = {bc0, bc1, bc2};

    for (int l = 0; l < 3; l++){
        k_agg<<<N, 128, 0, stream>>>(hx, rp, col, ag, N);
        k_gemm<<<N, 128, 0, stream>>>(ag, wcs[l], bcs[l], N);
        k_zero<<<1, 256, 0, stream>>>((int*)colsum, 128);
        k_zero<<<1, 256, 0, stream>>>((int*)colssq, 128);
        k_colstats<<<256, 256, 0, stream>>>(ag, colsum, colssq, N);
        k_meaninv<<<1, 128, 0, stream>>>(colsum, colssq, ninv, meanv, invv);
        k_bn<<<(NF + 255) / 256, 256, 0, stream>>>(ag, meanv, invv, hx, NF);
    }

    k_final<<<(N * 40 + 255) / 256, 256, 0, stream>>>(hx, wcl, bcl, d_out, N, flags);
}

// Round 5
// 654.373 us; speedup vs baseline: 2.4845x; 2.4845x over previous
//
#include <hip/hip_runtime.h>
#include <stdint.h>

typedef __attribute__((ext_vector_type(8))) short short8;    // MFMA A/B frag (8 bf16)
typedef __attribute__((ext_vector_type(4))) float floatx4;   // MFMA C/D frag

// ---------- bf16 helpers (manual, no hip_bf16 dependency) ----------
static __device__ __forceinline__ float b2f(uint16_t b){
    return __uint_as_float(((uint32_t)b) << 16);
}
static __device__ __forceinline__ uint16_t f2b(float f){
    uint32_t u = __float_as_uint(f);
    return (uint16_t)((u + 0x7fffu + ((u >> 16) & 1u)) >> 16);
}
static __device__ __forceinline__ float blo(uint32_t v){ return __uint_as_float(v << 16); }
static __device__ __forceinline__ float bhi(uint32_t v){ return __uint_as_float(v & 0xffff0000u); }
static __device__ __forceinline__ uint32_t pack2(float a, float b){
    return ((uint32_t)f2b(b) << 16) | (uint32_t)f2b(a);
}

// ---------- sentinel fill ----------
__global__ void k_sentinel(uint32_t* out, int nwords, uint32_t pat){
    int i = blockIdx.x * blockDim.x + threadIdx.x;
    if (i < nwords) out[i] = pat;
}

// ---------- dtype flags: flags[0]=edge_is_int64, flags[1]=x_is_bf16 ----------
__global__ void k_flags(const uint32_t* xw, const int* ei, int* flags){
    if (threadIdx.x != 0 || blockIdx.x != 0) return;
    int odd_nz = 0;
    for (int k = 0; k < 128; k++){
        if (ei[2 * k + 1] != 0) odd_nz = 1;
    }
    flags[0] = odd_nz ? 0 : 1;
    int big = 0;
    for (int k = 0; k < 128; k++){
        float lo = __uint_as_float(xw[k] << 16);
        if (!(fabsf(lo) <= 1024.0f)) big = 1;
    }
    flags[1] = big ? 0 : 1;
}

__global__ void k_zero(int* p, int n){
    int i = blockIdx.x * blockDim.x + threadIdx.x;
    if (i < n) p[i] = 0;
}

// ---------- CSR build ----------
__global__ void k_deg(const int* ei, int E, int* deg, const int* flags){
    int e = blockIdx.x * blockDim.x + threadIdx.x;
    if (e < E){
        int d = flags[0] ? ei[2 * e] : ei[e];
        atomicAdd(&deg[d], 1);
    }
}

// 3-phase parallel exclusive scan over deg[0..N)
__global__ void k_scan1(const int* deg, int N, int* bsum){
    __shared__ int s[256];
    int t = threadIdx.x;
    int i = blockIdx.x * 256 + t;
    s[t] = (i < N) ? deg[i] : 0;
    __syncthreads();
    for (int off = 128; off > 0; off >>= 1){
        if (t < off) s[t] += s[t + off];
        __syncthreads();
    }
    if (t == 0) bsum[blockIdx.x] = s[0];
}

__global__ void k_scan2(int* bsum, int nb, int* rp, int N){
    __shared__ int s[512];
    int t = threadIdx.x;
    int v = (t < nb) ? bsum[t] : 0;
    s[t] = v;
    __syncthreads();
    for (int off = 1; off < 512; off <<= 1){
        int u = (t >= off) ? s[t - off] : 0;
        __syncthreads();
        s[t] += u;
        __syncthreads();
    }
    if (t < nb) bsum[t] = s[t] - v;        // exclusive block prefix
    if (t == 511) rp[N] = s[511];          // total edge count
}

__global__ void k_scan3(const int* deg, int N, const int* bpre, int* rp, int* cur){
    __shared__ int s[256];
    int t = threadIdx.x;
    int i = blockIdx.x * 256 + t;
    int v = (i < N) ? deg[i] : 0;
    s[t] = v;
    __syncthreads();
    for (int off = 1; off < 256; off <<= 1){
        int u = (t >= off) ? s[t - off] : 0;
        __syncthreads();
        s[t] += u;
        __syncthreads();
    }
    if (i < N){
        int ex = bpre[blockIdx.x] + s[t] - v;
        rp[i] = ex;
        cur[i] = ex;
    }
}

__global__ void k_fill(const int* ei, int E, int* cur, int* col, const int* flags){
    int e = blockIdx.x * blockDim.x + threadIdx.x;
    if (e < E){
        int is64 = flags[0];
        int d = is64 ? ei[2 * e] : ei[e];
        int sv = is64 ? ei[2 * (E + e)] : ei[E + e];
        int p = atomicAdd(&cur[d], 1);
        col[p] = sv;
    }
}

// ---------- input conversions ----------
__global__ void k_cvt_x(const void* x, uint16_t* hx, int n, const int* flags){
    int i = blockIdx.x * blockDim.x + threadIdx.x;
    if (i >= n) return;
    if (flags[1]) hx[i] = ((const uint16_t*)x)[i];
    else          hx[i] = f2b(((const float*)x)[i]);
}

__global__ void k_cvt_f(const void* w, float* wc, int n, const int* flags){
    int i = blockIdx.x * blockDim.x + threadIdx.x;
    if (i >= n) return;
    if (flags[1]) wc[i] = b2f(((const uint16_t*)w)[i]);
    else          wc[i] = ((const float*)w)[i];
}

// ---------- W reorder into MFMA B-fragment order (bf16 out) ----------
// Wf[((kt*ntiles+nt)*64 + lane)*8 + j] = W[kt*32 + (lane>>4)*8 + j][nt*16 + (lane&15)]
__global__ void k_prep_w(const void* W, int C, int ntiles, uint16_t* Wf, const int* flags){
    int idx = blockIdx.x * blockDim.x + threadIdx.x;
    int total = 4 * ntiles * 512;
    if (idx >= total) return;
    int j = idx & 7;
    int lane = (idx >> 3) & 63;
    int nt = (idx >> 9) % ntiles;
    int kt = idx / (512 * ntiles);
    int k = kt * 32 + (lane >> 4) * 8 + j;
    int n = nt * 16 + (lane & 15);
    uint16_t v = 0;
    if (n < C){
        v = flags[1] ? ((const uint16_t*)W)[k * C + n]
                     : f2b(((const float*)W)[k * C + n]);
    }
    Wf[idx] = v;
}

// ---------- aggregation: ag[i,:] = hx[i,:] + sum_{j in nbr(i)} hx[j,:] ----------
// 16 lanes per node, uint4 (8 bf16) per lane
__global__ void k_agg(const uint16_t* hx, const int* rp, const int* col,
                      uint16_t* ag, int N){
    int t = threadIdx.x;
    int l16 = t & 15;
    int i = blockIdx.x * 16 + (t >> 4);
    if (i >= N) return;
    const uint4* base = (const uint4*)hx;   // 16 uint4 per 128-feature row
    uint4 v = base[(size_t)i * 16 + l16];
    float a0 = blo(v.x), a1 = bhi(v.x), a2 = blo(v.y), a3 = bhi(v.y);
    float a4 = blo(v.z), a5 = bhi(v.z), a6 = blo(v.w), a7 = bhi(v.w);
    int s = rp[i], e = rp[i + 1];
    for (int k = s; k < e; k++){
        int j = col[k];
        uint4 w = base[(size_t)j * 16 + l16];
        a0 += blo(w.x); a1 += bhi(w.x); a2 += blo(w.y); a3 += bhi(w.y);
        a4 += blo(w.z); a5 += bhi(w.z); a6 += blo(w.w); a7 += bhi(w.w);
    }
    uint4 o;
    o.x = pack2(a0, a1); o.y = pack2(a2, a3);
    o.z = pack2(a4, a5); o.w = pack2(a6, a7);
    ((uint4*)ag)[(size_t)i * 16 + l16] = o;
}

// ---------- MFMA GEMM: A(N x 128, bf16) @ W(128 x 128) + bias -> bf16, in place ----------
__global__ void k_gemm(uint16_t* A, const uint16_t* Wf, const float* bias, int N){
    __shared__ __align__(16) uint16_t wlds[16384];   // 32 KB fragment-ordered W
    int t = threadIdx.x;
    {
        const uint4* s = (const uint4*)Wf;
        uint4* d = (uint4*)wlds;
        for (int i = t; i < 2048; i += 256) d[i] = s[i];
    }
    __syncthreads();
    int lane = t & 63, wave = t >> 6;
    int m = lane & 15, q = lane >> 4;
    int row_base = blockIdx.x * 64 + wave * 16;
    int arow = row_base + m;
    if (arow >= N) arow = N - 1;   // clamped lanes' results discarded below
    short8 afrag[4];
    const short8* ap = (const short8*)(A + (size_t)arow * 128);
    #pragma unroll
    for (int kt = 0; kt < 4; kt++) afrag[kt] = ap[kt * 4 + q];

    floatx4 acc[8];
    #pragma unroll
    for (int nt = 0; nt < 8; nt++) acc[nt] = (floatx4){0.f, 0.f, 0.f, 0.f};
    const short8* wl = (const short8*)wlds;
    #pragma unroll
    for (int kt = 0; kt < 4; kt++){
        #pragma unroll
        for (int nt = 0; nt < 8; nt++){
            acc[nt] = __builtin_amdgcn_mfma_f32_16x16x32_bf16(afrag[kt], wl[(kt * 8 + nt) * 64 + lane], acc[nt], 0, 0, 0);
        }
    }
    #pragma unroll
    for (int nt = 0; nt < 8; nt++){
        int ccol = nt * 16 + m;                    // C/D: col = lane&15
        float bv = bias[ccol];
        #pragma unroll
        for (int r = 0; r < 4; r++){
            int grow = row_base + q * 4 + r;       // C/D: row = (lane>>4)*4 + r
            if (grow < N){
                A[(size_t)grow * 128 + ccol] = f2b(acc[nt][r] + bv);
            }
        }
    }
}

// ---------- column stats ----------
__global__ void k_colstats(const uint16_t* Y, float* colsum, float* colssq, int N){
    int t = threadIdx.x;
    int c = t & 127;
    int half = t >> 7;
    float s = 0.f, ss = 0.f;
    for (int r = blockIdx.x * 2 + half; r < N; r += 512){
        float y = b2f(Y[(size_t)r * 128 + c]);
        s += y; ss += y * y;
    }
    atomicAdd(&colsum[c], s);
    atomicAdd(&colssq[c], ss);
}

__global__ void k_meaninv(const float* colsum, const float* colssq, float ninv,
                          float* meanv, float* invv){
    int c = threadIdx.x;
    float m = colsum[c] * ninv;
    float v = colssq[c] * ninv - m * m;
    meanv[c] = m;
    invv[c] = rsqrtf(v + 1e-5f);
}

// ---------- BN + ReLU (uint2 = 4 bf16 per thread) ----------
__global__ void k_bn(const uint16_t* Y, const float* meanv, const float* invv,
                     uint16_t* hx, int nquads){
    int idx = blockIdx.x * blockDim.x + threadIdx.x;
    if (idx >= nquads) return;
    int f = (idx & 31) * 4;
    uint2 v = ((const uint2*)Y)[idx];
    float y0 = blo(v.x), y1 = bhi(v.x), y2 = blo(v.y), y3 = bhi(v.y);
    float r0 = fmaxf((y0 - meanv[f + 0]) * invv[f + 0], 0.f);
    float r1 = fmaxf((y1 - meanv[f + 1]) * invv[f + 1], 0.f);
    float r2 = fmaxf((y2 - meanv[f + 2]) * invv[f + 2], 0.f);
    float r3 = fmaxf((y3 - meanv[f + 3]) * invv[f + 3], 0.f);
    uint2 o;
    o.x = pack2(r0, r1);
    o.y = pack2(r2, r3);
    ((uint2*)hx)[idx] = o;
}

// ---------- final MFMA GEMM: hx(N x 128) @ Wl(128 x 40) + bias -> out ----------
__global__ void k_out(const uint16_t* A, const uint16_t* Wf, const float* bias,
                      void* out, int N, const int* flags){
    __shared__ __align__(16) uint16_t wlds[6144];   // 128 x 48 fragment-ordered
    int t = threadIdx.x;
    {
        const uint4* s = (const uint4*)Wf;
        uint4* d = (uint4*)wlds;
        for (int i = t; i < 768; i += 256) d[i] = s[i];
    }
    __syncthreads();
    int lane = t & 63, wave = t >> 6;
    int m = lane & 15, q = lane >> 4;
    int row_base = blockIdx.x * 64 + wave * 16;
    int arow = row_base + m;
    if (arow >= N) arow = N - 1;
    short8 afrag[4];
    const short8* ap = (const short8*)(A + (size_t)arow * 128);
    #pragma unroll
    for (int kt = 0; kt < 4; kt++) afrag[kt] = ap[kt * 4 + q];
    floatx4 acc[3];
    #pragma unroll
    for (int nt = 0; nt < 3; nt++) acc[nt] = (floatx4){0.f, 0.f, 0.f, 0.f};
    const short8* wl = (const short8*)wlds;
    #pragma unroll
    for (int kt = 0; kt < 4; kt++){
        #pragma unroll
        for (int nt = 0; nt < 3; nt++){
            acc[nt] = __builtin_amdgcn_mfma_f32_16x16x32_bf16(afrag[kt], wl[(kt * 3 + nt) * 64 + lane], acc[nt], 0, 0, 0);
        }
    }
    int isbf = flags[1];
    #pragma unroll
    for (int nt = 0; nt < 3; nt++){
        int ccol = nt * 16 + m;
        if (ccol < 40){
            float bv = bias[ccol];
            #pragma unroll
            for (int r = 0; r < 4; r++){
                int grow = row_base + q * 4 + r;
                if (grow < N){
                    float y = acc[nt][r] + bv;
                    if (isbf) ((uint16_t*)out)[(size_t)grow * 40 + ccol] = f2b(y);
                    else      ((float*)out)[(size_t)grow * 40 + ccol] = y;
                }
            }
        }
    }
}

extern "C" void kernel_launch(void* const* d_in, const int* in_sizes, int n_in,
                              void* d_out, int out_size, void* d_ws, size_t ws_size,
                              hipStream_t stream){
    (void)n_in;
    const void* x  = d_in[0];
    const int* ei  = (const int*)d_in[1];
    const void* W0 = d_in[2];
    const void* b0 = d_in[3];
    const void* W1 = d_in[4];
    const void* b1 = d_in[5];
    const void* W2 = d_in[6];
    const void* b2 = d_in[7];
    const void* Wl = d_in[8];
    const void* bl = d_in[9];

    const int N = in_sizes[0] / 128;
    const int E = in_sizes[1] / 2;
    const int NF = N * 128;
    const int NB = (N + 255) / 256;     // scan blocks (<= 512 assumed; N=100k -> 391)

    // ---- workspace layout ----
    char* ws = (char*)d_ws;
    size_t off = 0;
    uint16_t* hx = (uint16_t*)(ws + off); off += ((size_t)NF * 2 + 255) & ~(size_t)255;
    uint16_t* ag = (uint16_t*)(ws + off); off += ((size_t)NF * 2 + 255) & ~(size_t)255;
    int* col     = (int*)(ws + off);      off += ((size_t)E * 4 + 255) & ~(size_t)255;
    int* rp      = (int*)(ws + off);      off += ((size_t)(N + 1) * 4 + 255) & ~(size_t)255;
    int* cur     = (int*)(ws + off);      off += ((size_t)N * 4 + 255) & ~(size_t)255;
    int* deg     = (int*)(ws + off);      off += ((size_t)N * 4 + 255) & ~(size_t)255;
    int* bsum    = (int*)(ws + off);      off += 512 * 4;
    int* flags   = (int*)(ws + off);      off += 256;
    uint16_t* Wf0 = (uint16_t*)(ws + off); off += 16384 * 2;
    uint16_t* Wf1 = (uint16_t*)(ws + off); off += 16384 * 2;
    uint16_t* Wf2 = (uint16_t*)(ws + off); off += 16384 * 2;
    uint16_t* Wfl = (uint16_t*)(ws + off); off += 6144 * 2;
    float* bc0   = (float*)(ws + off);    off += 512;
    float* bc1   = (float*)(ws + off);    off += 512;
    float* bc2   = (float*)(ws + off);    off += 512;
    float* bcl   = (float*)(ws + off);    off += 256;
    float* colsum = (float*)(ws + off);   off += 512;
    float* colssq = (float*)(ws + off);   off += 512;   // adjacent to colsum: zeroed together
    float* meanv  = (float*)(ws + off);   off += 512;
    float* invv   = (float*)(ws + off);   off += 512;
    const size_t required = off;

    const int nwords = out_size / 2;
    const int fill_blocks = (nwords + 255) / 256;

    if (ws_size < required){
        k_sentinel<<<fill_blocks, 256, 0, stream>>>((uint32_t*)d_out, nwords, 0x40004000u); // 2.0
        return;
    }
    k_sentinel<<<fill_blocks, 256, 0, stream>>>((uint32_t*)d_out, nwords, 0x3F803F80u);     // 1.0

    // ---- flags + CSR ----
    k_flags<<<1, 64, 0, stream>>>((const uint32_t*)x, ei, flags);
    k_zero<<<(N + 255) / 256, 256, 0, stream>>>(deg, N);
    k_deg<<<(E + 255) / 256, 256, 0, stream>>>(ei, E, deg, flags);
    k_scan1<<<NB, 256, 0, stream>>>(deg, N, bsum);
    k_scan2<<<1, 512, 0, stream>>>(bsum, NB, rp, N);
    k_scan3<<<NB, 256, 0, stream>>>(deg, N, bsum, rp, cur);
    k_fill<<<(E + 255) / 256, 256, 0, stream>>>(ei, E, cur, col, flags);

    // ---- conversions / weight prep ----
    k_cvt_x<<<(NF + 255) / 256, 256, 0, stream>>>(x, hx, NF, flags);
    k_prep_w<<<64, 256, 0, stream>>>(W0, 128, 8, Wf0, flags);
    k_prep_w<<<64, 256, 0, stream>>>(W1, 128, 8, Wf1, flags);
    k_prep_w<<<64, 256, 0, stream>>>(W2, 128, 8, Wf2, flags);
    k_prep_w<<<24, 256, 0, stream>>>(Wl, 40, 3, Wfl, flags);
    k_cvt_f<<<1, 128, 0, stream>>>(b0, bc0, 128, flags);
    k_cvt_f<<<1, 128, 0, stream>>>(b1, bc1, 128, flags);
    k_cvt_f<<<1, 128, 0, stream>>>(b2, bc2, 128, flags);
    k_cvt_f<<<1, 64, 0, stream>>>(bl, bcl, 40, flags);

    const float ninv = 1.0f / (float)N;
    const int agg_blocks  = (N + 15) / 16;
    const int gemm_blocks = (N + 63) / 64;
    const int nquads = NF / 4;
    float* bcs[3] = {bc0, bc1, bc2};
    uint16_t* Wfs[3] = {Wf0, Wf1, Wf2};

    for (int l = 0; l < 3; l++){
        k_agg<<<agg_blocks, 256, 0, stream>>>(hx, rp, col, ag, N);
        k_gemm<<<gemm_blocks, 256, 0, stream>>>(ag, Wfs[l], bcs[l], N);
        k_zero<<<1, 256, 0, stream>>>((int*)colsum, 256);   // colsum + colssq
        k_colstats<<<256, 256, 0, stream>>>(ag, colsum, colssq, N);
        k_meaninv<<<1, 128, 0, stream>>>(colsum, colssq, ninv, meanv, invv);
        k_bn<<<(nquads + 255) / 256, 256, 0, stream>>>(ag, meanv, invv, hx, nquads);
    }

    k_out<<<gemm_blocks, 256, 0, stream>>>(hx, Wfl, bcl, d_out, N, flags);
}

// Round 7
// 540.880 us; speedup vs baseline: 3.0058x; 1.2098x over previous
//
#include <hip/hip_runtime.h>
#include <stdint.h>

typedef __attribute__((ext_vector_type(8))) short short8;    // MFMA A/B frag (8 bf16)
typedef __attribute__((ext_vector_type(4))) float floatx4;   // MFMA C/D frag

// ---------- bf16 helpers ----------
static __device__ __forceinline__ float b2f(uint16_t b){
    return __uint_as_float(((uint32_t)b) << 16);
}
static __device__ __forceinline__ uint16_t f2b(float f){
    uint32_t u = __float_as_uint(f);
    return (uint16_t)((u + 0x7fffu + ((u >> 16) & 1u)) >> 16);
}
static __device__ __forceinline__ float blo(uint32_t v){ return __uint_as_float(v << 16); }
static __device__ __forceinline__ float bhi(uint32_t v){ return __uint_as_float(v & 0xffff0000u); }
static __device__ __forceinline__ uint32_t pack2(float a, float b){
    return ((uint32_t)f2b(b) << 16) | (uint32_t)f2b(a);
}

// ---------- sentinel (only used when ws too small) ----------
__global__ void k_sentinel(uint32_t* out, int nwords, uint32_t pat){
    int i = blockIdx.x * blockDim.x + threadIdx.x;
    if (i < nwords) out[i] = pat;
}

// ---------- dtype flags: flags[0]=edge_is_int64, flags[1]=x_is_bf16 ----------
__global__ void k_flags(const uint32_t* xw, const int* ei, int* flags){
    if (threadIdx.x != 0 || blockIdx.x != 0) return;
    int odd_nz = 0;
    for (int k = 0; k < 128; k++){
        if (ei[2 * k + 1] != 0) odd_nz = 1;
    }
    flags[0] = odd_nz ? 0 : 1;
    int big = 0;
    for (int k = 0; k < 128; k++){
        float lo = __uint_as_float(xw[k] << 16);
        if (!(fabsf(lo) <= 1024.0f)) big = 1;
    }
    flags[1] = big ? 0 : 1;
}

// ---------- zero deg[N] + stats[768] in one launch ----------
__global__ void k_zero2(int* deg, int N, float* stats){
    int i = blockIdx.x * blockDim.x + threadIdx.x;
    if (i < N) deg[i] = 0;
    else if (i < N + 768) stats[i - N] = 0.f;
}

// ---------- CSR build ----------
__global__ void k_deg(const int* ei, int E, int* deg, const int* flags){
    int e = blockIdx.x * blockDim.x + threadIdx.x;
    if (e < E){
        int d = flags[0] ? ei[2 * e] : ei[e];
        atomicAdd(&deg[d], 1);
    }
}

__global__ void k_scan1(const int* deg, int N, int* bsum){
    __shared__ int s[256];
    int t = threadIdx.x;
    int i = blockIdx.x * 256 + t;
    s[t] = (i < N) ? deg[i] : 0;
    __syncthreads();
    for (int off = 128; off > 0; off >>= 1){
        if (t < off) s[t] += s[t + off];
        __syncthreads();
    }
    if (t == 0) bsum[blockIdx.x] = s[0];
}

__global__ void k_scan2(int* bsum, int nb, int* rp, int N){
    __shared__ int s[512];
    int t = threadIdx.x;
    int v = (t < nb) ? bsum[t] : 0;
    s[t] = v;
    __syncthreads();
    for (int off = 1; off < 512; off <<= 1){
        int u = (t >= off) ? s[t - off] : 0;
        __syncthreads();
        s[t] += u;
        __syncthreads();
    }
    if (t < nb) bsum[t] = s[t] - v;
    if (t == 511) rp[N] = s[511];
}

__global__ void k_scan3(const int* deg, int N, const int* bpre, int* rp, int* cur){
    __shared__ int s[256];
    int t = threadIdx.x;
    int i = blockIdx.x * 256 + t;
    int v = (i < N) ? deg[i] : 0;
    s[t] = v;
    __syncthreads();
    for (int off = 1; off < 256; off <<= 1){
        int u = (t >= off) ? s[t - off] : 0;
        __syncthreads();
        s[t] += u;
        __syncthreads();
    }
    if (i < N){
        int ex = bpre[blockIdx.x] + s[t] - v;
        rp[i] = ex;
        cur[i] = ex;
    }
}

__global__ void k_fill(const int* ei, int E, int* cur, int* col, const int* flags){
    int e = blockIdx.x * blockDim.x + threadIdx.x;
    if (e < E){
        int is64 = flags[0];
        int d = is64 ? ei[2 * e] : ei[e];
        int sv = is64 ? ei[2 * (E + e)] : ei[E + e];
        int p = atomicAdd(&cur[d], 1);
        col[p] = sv;
    }
}

// ---------- input conversion ----------
__global__ void k_cvt_x(const void* x, uint16_t* hx, int n, const int* flags){
    int i = blockIdx.x * blockDim.x + threadIdx.x;
    if (i >= n) return;
    if (flags[1]) hx[i] = ((const uint16_t*)x)[i];
    else          hx[i] = f2b(((const float*)x)[i]);
}

// ---------- all W fragment reorders in ONE launch ----------
// block ranges: [0,64) W0, [64,128) W1, [128,192) W2, [192,216) Wl
__global__ void k_prep_all(const void* W0, const void* W1, const void* W2, const void* Wl,
                           uint16_t* Wf0, uint16_t* Wf1, uint16_t* Wf2, uint16_t* Wfl,
                           const int* flags){
    int b = blockIdx.x;
    const void* W; uint16_t* Wf; int C, ntiles, lb;
    if (b < 64)        { W = W0; Wf = Wf0; C = 128; ntiles = 8; lb = b; }
    else if (b < 128)  { W = W1; Wf = Wf1; C = 128; ntiles = 8; lb = b - 64; }
    else if (b < 192)  { W = W2; Wf = Wf2; C = 128; ntiles = 8; lb = b - 128; }
    else               { W = Wl; Wf = Wfl; C = 40;  ntiles = 3; lb = b - 192; }
    int idx = lb * 256 + threadIdx.x;
    int total = 4 * ntiles * 512;
    if (idx >= total) return;
    int j = idx & 7;
    int lane = (idx >> 3) & 63;
    int nt = (idx >> 9) % ntiles;
    int kt = idx / (512 * ntiles);
    int k = kt * 32 + (lane >> 4) * 8 + j;
    int n = nt * 16 + (lane & 15);
    uint16_t v = 0;
    if (n < C){
        v = flags[1] ? ((const uint16_t*)W)[k * C + n]
                     : f2b(((const float*)W)[k * C + n]);
    }
    Wf[idx] = v;
}

// ---------- all bias conversions in ONE launch (bc[424]: b0,b1,b2 @128 each, bl@384) ----------
__global__ void k_cvt_bias(const void* b0, const void* b1, const void* b2, const void* bl,
                           float* bc, const int* flags){
    int i = blockIdx.x * blockDim.x + threadIdx.x;
    if (i >= 424) return;
    const void* src; int li;
    if (i < 128)      { src = b0; li = i; }
    else if (i < 256) { src = b1; li = i - 128; }
    else if (i < 384) { src = b2; li = i - 256; }
    else              { src = bl; li = i - 384; }
    bc[i] = flags[1] ? b2f(((const uint16_t*)src)[li]) : ((const float*)src)[li];
}

// ---------- aggregation with lazy BN+ReLU on read ----------
// out[i,:] = T(Yin[i,:]) + sum_{j in nbr(i)} T(Yin[j,:]),
// T = identity (apply_bn=0) or relu((y-mean)*inv) using st[0:128]=colsum, st[128:256]=colssq
__global__ __launch_bounds__(256) void k_agg(const uint16_t* __restrict__ Yin,
                                             const int* __restrict__ rp,
                                             const int* __restrict__ col,
                                             uint16_t* __restrict__ out, int N,
                                             const float* __restrict__ st,
                                             int apply_bn, float ninv){
    int t = threadIdx.x;
    int l16 = t & 15;
    int i = blockIdx.x * 16 + (t >> 4);
    if (i >= N) return;
    float mm[8], iv[8];
    if (apply_bn){
        int f0 = l16 * 8;
        #pragma unroll
        for (int j = 0; j < 8; j++){
            float sv = st[f0 + j];
            float qv = st[128 + f0 + j];
            float m = sv * ninv;
            float var = qv * ninv - m * m;
            mm[j] = m;
            iv[j] = rsqrtf(var + 1e-5f);
        }
    }
    const uint4* base = (const uint4*)Yin;
    float a[8] = {0.f, 0.f, 0.f, 0.f, 0.f, 0.f, 0.f, 0.f};
    int s0 = rp[i], e0 = rp[i + 1];
    for (int k = s0 - 1; k < e0; k++){           // k==s0-1 encodes the self loop
        int j = (k < s0) ? i : col[k];
        uint4 w = base[(size_t)j * 16 + l16];
        float v[8] = {blo(w.x), bhi(w.x), blo(w.y), bhi(w.y),
                      blo(w.z), bhi(w.z), blo(w.w), bhi(w.w)};
        if (apply_bn){
            #pragma unroll
            for (int jj = 0; jj < 8; jj++) v[jj] = fmaxf((v[jj] - mm[jj]) * iv[jj], 0.f);
        }
        #pragma unroll
        for (int jj = 0; jj < 8; jj++) a[jj] += v[jj];
    }
    uint4 o;
    o.x = pack2(a[0], a[1]); o.y = pack2(a[2], a[3]);
    o.z = pack2(a[4], a[5]); o.w = pack2(a[6], a[7]);
    ((uint4*)out)[(size_t)i * 16 + l16] = o;
}

// ---------- MFMA GEMM (in place) + bias + FUSED column stats ----------
__global__ __launch_bounds__(256) void k_gemm(uint16_t* __restrict__ A,
                                              const uint16_t* __restrict__ Wf,
                                              const float* __restrict__ bias,
                                              float* __restrict__ st, int N){
    __shared__ __align__(16) uint16_t wlds[16384];
    __shared__ float sh_sum[128], sh_ssq[128];
    int t = threadIdx.x;
    if (t < 128){ sh_sum[t] = 0.f; sh_ssq[t] = 0.f; }
    {
        const uint4* s = (const uint4*)Wf;
        uint4* d = (uint4*)wlds;
        for (int i = t; i < 2048; i += 256) d[i] = s[i];
    }
    __syncthreads();
    int lane = t & 63, wave = t >> 6;
    int m = lane & 15, q = lane >> 4;
    int row_base = blockIdx.x * 64 + wave * 16;
    int arow = row_base + m;
    if (arow >= N) arow = N - 1;
    short8 afrag[4];
    const short8* ap = (const short8*)(A + (size_t)arow * 128);
    #pragma unroll
    for (int kt = 0; kt < 4; kt++) afrag[kt] = ap[kt * 4 + q];

    floatx4 acc[8];
    #pragma unroll
    for (int nt = 0; nt < 8; nt++) acc[nt] = (floatx4){0.f, 0.f, 0.f, 0.f};
    const short8* wl = (const short8*)wlds;
    #pragma unroll
    for (int kt = 0; kt < 4; kt++){
        #pragma unroll
        for (int nt = 0; nt < 8; nt++){
            acc[nt] = __builtin_amdgcn_mfma_f32_16x16x32_bf16(afrag[kt], wl[(kt * 8 + nt) * 64 + lane], acc[nt], 0, 0, 0);
        }
    }
    #pragma unroll
    for (int nt = 0; nt < 8; nt++){
        int ccol = nt * 16 + m;
        float bv = bias[ccol];
        float s = 0.f, ss = 0.f;
        #pragma unroll
        for (int r = 0; r < 4; r++){
            int grow = row_base + q * 4 + r;
            if (grow < N){
                float y = acc[nt][r] + bv;
                A[(size_t)grow * 128 + ccol] = f2b(y);
                s += y;
                ss += y * y;
            }
        }
        s += __shfl_xor(s, 16); s += __shfl_xor(s, 32);
        ss += __shfl_xor(ss, 16); ss += __shfl_xor(ss, 32);
        if (q == 0){
            atomicAdd(&sh_sum[ccol], s);
            atomicAdd(&sh_ssq[ccol], ss);
        }
    }
    __syncthreads();
    if (t < 128){
        atomicAdd(&st[t], sh_sum[t]);
        atomicAdd(&st[128 + t], sh_ssq[t]);
    }
}

// ---------- final GEMM with BN+ReLU applied to A on read ----------
__global__ __launch_bounds__(256) void k_out(const uint16_t* __restrict__ A,
                                             const uint16_t* __restrict__ Wf,
                                             const float* __restrict__ bias,
                                             const float* __restrict__ st, float ninv,
                                             void* __restrict__ out, int N,
                                             const int* __restrict__ flags){
    __shared__ __align__(16) uint16_t wlds[6144];
    __shared__ float s_m[128], s_iv[128];
    int t = threadIdx.x;
    {
        const uint4* s = (const uint4*)Wf;
        uint4* d = (uint4*)wlds;
        for (int i = t; i < 768; i += 256) d[i] = s[i];
    }
    if (t < 128){
        float m = st[t] * ninv;
        float var = st[128 + t] * ninv - m * m;
        s_m[t] = m;
        s_iv[t] = rsqrtf(var + 1e-5f);
    }
    __syncthreads();
    int lane = t & 63, wave = t >> 6;
    int m = lane & 15, q = lane >> 4;
    int row_base = blockIdx.x * 64 + wave * 16;
    int arow = row_base + m;
    if (arow >= N) arow = N - 1;
    short8 afrag[4];
    const uint4* ap = (const uint4*)(A + (size_t)arow * 128);
    #pragma unroll
    for (int kt = 0; kt < 4; kt++){
        uint4 u = ap[kt * 4 + q];
        float v[8] = {blo(u.x), bhi(u.x), blo(u.y), bhi(u.y),
                      blo(u.z), bhi(u.z), blo(u.w), bhi(u.w)};
        int c0 = kt * 32 + q * 8;
        #pragma unroll
        for (int j = 0; j < 8; j++) v[j] = fmaxf((v[j] - s_m[c0 + j]) * s_iv[c0 + j], 0.f);
        uint4 o;
        o.x = pack2(v[0], v[1]); o.y = pack2(v[2], v[3]);
        o.z = pack2(v[4], v[5]); o.w = pack2(v[6], v[7]);
        afrag[kt] = *(short8*)&o;
    }
    floatx4 acc[3];
    #pragma unroll
    for (int nt = 0; nt < 3; nt++) acc[nt] = (floatx4){0.f, 0.f, 0.f, 0.f};
    const short8* wl = (const short8*)wlds;
    #pragma unroll
    for (int kt = 0; kt < 4; kt++){
        #pragma unroll
        for (int nt = 0; nt < 3; nt++){
            acc[nt] = __builtin_amdgcn_mfma_f32_16x16x32_bf16(afrag[kt], wl[(kt * 3 + nt) * 64 + lane], acc[nt], 0, 0, 0);
        }
    }
    int isbf = flags[1];
    #pragma unroll
    for (int nt = 0; nt < 3; nt++){
        int ccol = nt * 16 + m;
        if (ccol < 40){
            float bv = bias[ccol];
            #pragma unroll
            for (int r = 0; r < 4; r++){
                int grow = row_base + q * 4 + r;
                if (grow < N){
                    float y = acc[nt][r] + bv;
                    if (isbf) ((uint16_t*)out)[(size_t)grow * 40 + ccol] = f2b(y);
                    else      ((float*)out)[(size_t)grow * 40 + ccol] = y;
                }
            }
        }
    }
}

extern "C" void kernel_launch(void* const* d_in, const int* in_sizes, int n_in,
                              void* d_out, int out_size, void* d_ws, size_t ws_size,
                              hipStream_t stream){
    (void)n_in;
    const void* x  = d_in[0];
    const int* ei  = (const int*)d_in[1];
    const void* W0 = d_in[2];
    const void* b0 = d_in[3];
    const void* W1 = d_in[4];
    const void* b1 = d_in[5];
    const void* W2 = d_in[6];
    const void* b2 = d_in[7];
    const void* Wl = d_in[8];
    const void* bl = d_in[9];

    const int N = in_sizes[0] / 128;
    const int E = in_sizes[1] / 2;
    const int NF = N * 128;
    const int NB = (N + 255) / 256;

    // ---- workspace layout ----
    char* ws = (char*)d_ws;
    size_t off = 0;
    uint16_t* hx = (uint16_t*)(ws + off); off += ((size_t)NF * 2 + 255) & ~(size_t)255;
    uint16_t* ag = (uint16_t*)(ws + off); off += ((size_t)NF * 2 + 255) & ~(size_t)255;
    int* col     = (int*)(ws + off);      off += ((size_t)E * 4 + 255) & ~(size_t)255;
    int* rp      = (int*)(ws + off);      off += ((size_t)(N + 1) * 4 + 255) & ~(size_t)255;
    int* cur     = (int*)(ws + off);      off += ((size_t)N * 4 + 255) & ~(size_t)255;
    int* deg     = (int*)(ws + off);      off += ((size_t)N * 4 + 255) & ~(size_t)255;
    int* bsum    = (int*)(ws + off);      off += 512 * 4;
    int* flags   = (int*)(ws + off);      off += 256;
    uint16_t* Wf0 = (uint16_t*)(ws + off); off += 16384 * 2;
    uint16_t* Wf1 = (uint16_t*)(ws + off); off += 16384 * 2;
    uint16_t* Wf2 = (uint16_t*)(ws + off); off += 16384 * 2;
    uint16_t* Wfl = (uint16_t*)(ws + off); off += 6144 * 2;
    float* bc    = (float*)(ws + off);    off += 424 * 4 + 160;
    float* stats = (float*)(ws + off);    off += 768 * 4;   // 3 layers x (colsum[128], colssq[128])
    const size_t required = off;

    if (ws_size < required){
        int nwords = out_size / 2;
        k_sentinel<<<(nwords + 255) / 256, 256, 0, stream>>>((uint32_t*)d_out, nwords, 0x40004000u);
        return;
    }

    // ---- flags, zeroing, CSR ----
    k_flags<<<1, 64, 0, stream>>>((const uint32_t*)x, ei, flags);
    k_zero2<<<(N + 768 + 255) / 256, 256, 0, stream>>>(deg, N, stats);
    k_deg<<<(E + 255) / 256, 256, 0, stream>>>(ei, E, deg, flags);
    k_scan1<<<NB, 256, 0, stream>>>(deg, N, bsum);
    k_scan2<<<1, 512, 0, stream>>>(bsum, NB, rp, N);
    k_scan3<<<NB, 256, 0, stream>>>(deg, N, bsum, rp, cur);
    k_fill<<<(E + 255) / 256, 256, 0, stream>>>(ei, E, cur, col, flags);

    // ---- conversions / weight prep ----
    k_cvt_x<<<(NF + 255) / 256, 256, 0, stream>>>(x, hx, NF, flags);
    k_prep_all<<<216, 256, 0, stream>>>(W0, W1, W2, Wl, Wf0, Wf1, Wf2, Wfl, flags);
    k_cvt_bias<<<2, 256, 0, stream>>>(b0, b1, b2, bl, bc, flags);

    const float ninv = 1.0f / (float)N;
    const int agg_blocks  = (N + 15) / 16;
    const int gemm_blocks = (N + 63) / 64;

    // layer 0: agg(x) -> ag, gemm in place (Y0 in ag), stats0
    k_agg<<<agg_blocks, 256, 0, stream>>>(hx, rp, col, ag, N, stats, 0, ninv);
    k_gemm<<<gemm_blocks, 256, 0, stream>>>(ag, Wf0, bc, stats, N);
    // layer 1: agg(bn0(Y0)) -> hx, gemm in place (Y1 in hx), stats1
    k_agg<<<agg_blocks, 256, 0, stream>>>(ag, rp, col, hx, N, stats, 1, ninv);
    k_gemm<<<gemm_blocks, 256, 0, stream>>>(hx, Wf1, bc + 128, stats + 256, N);
    // layer 2: agg(bn1(Y1)) -> ag, gemm in place (Y2 in ag), stats2
    k_agg<<<agg_blocks, 256, 0, stream>>>(hx, rp, col, ag, N, stats + 256, 1, ninv);
    k_gemm<<<gemm_blocks, 256, 0, stream>>>(ag, Wf2, bc + 256, stats + 512, N);
    // final: out = bn2(Y2)relu @ Wl + bl
    k_out<<<gemm_blocks, 256, 0, stream>>>(ag, Wfl, bc + 384, stats + 512, ninv, d_out, N, flags);
}